// Round 4
// baseline (939.190 us; speedup 1.0000x reference)
//
#include <hip/hip_runtime.h>

// ---------------- problem constants ----------------
#define N_TOK 8192      // B*S tokens
#define H_DIM 1024
#define I_DIM 2048
#define N_EXP 8
#define TOPK  2
#define CAP   17408     // 16384 + 8*128 (per-expert padding to 128)
#define MT_MAX 136      // CAP / 128

// ---------------- workspace layout (bytes) ----------------
#define OFF_TOPK_I 0u          // 16384 i32
#define OFF_TOPK_W 65536u      // 16384 f32 (RAW softmax probs of chosen experts)
#define OFF_COUNTS 131072u     // 8 i32
#define OFF_LOAD   131104u     // 8 f32
#define OFF_CURSOR 131136u     // 8 i32
#define OFF_PO     131168u     // 16 i32
#define OFF_TILE_E 131232u     // 152 i32 (136 used)
#define OFF_BTOK   131840u     // 17408 i32
#define OFF_BW     201472u     // 17408 f32
#define CTRL_BYTES 271104u     // memset covers everything above
#define OFF_TSLOT  271104u     // 16384 i32 — fully overwritten by k_bucket, no memset
#define OFF_WGT  1048576u                      // 8*2048*1024*2 = 33554432
#define OFF_WUT  (OFF_WGT + 33554432u)
#define OFF_WDT  (OFF_WUT + 33554432u)
#define OFF_HB   (OFF_WDT + 33554432u)         // 17408*2048*2 = 71303168
#define OFF_XB   (OFF_HB + 71303168u)          // 8192*1024*2 = 16777216 (x in bf16)
// obuf (17408*1024 bf16 = 35.7 MB) reuses WGT+WUT (dead after gemm1)

typedef __attribute__((ext_vector_type(8))) short bf16x8;
typedef __attribute__((ext_vector_type(8))) unsigned short u16x8;
typedef __attribute__((ext_vector_type(4))) unsigned short u16x4;
typedef __attribute__((ext_vector_type(4))) float f32x4;

#define BAR() __builtin_amdgcn_s_barrier()
#define PRIO1() __builtin_amdgcn_s_setprio(1)
#define PRIO0() __builtin_amdgcn_s_setprio(0)
#define WAITV0() asm volatile("s_waitcnt vmcnt(0)" ::: "memory")

__device__ __forceinline__ unsigned short f2bf(float f) {
  union { float f; unsigned int u; } v; v.f = f;
  unsigned int r = (v.u + 0x7FFFu + ((v.u >> 16) & 1u)) >> 16;
  return (unsigned short)r;
}
__device__ __forceinline__ float bf2f(unsigned short u) {
  union { unsigned int u; float f; } v; v.u = ((unsigned int)u) << 16;
  return v.f;
}
__device__ __forceinline__ u16x8 pack8(float4 a, float4 b) {
  u16x8 r;
  r[0] = f2bf(a.x); r[1] = f2bf(a.y); r[2] = f2bf(a.z); r[3] = f2bf(a.w);
  r[4] = f2bf(b.x); r[5] = f2bf(b.y); r[6] = f2bf(b.z); r[7] = f2bf(b.w);
  return r;
}
__device__ __forceinline__ f32x4 mfma32(bf16x8 a, bf16x8 b, f32x4 c) {
  return __builtin_amdgcn_mfma_f32_16x16x32_bf16(a, b, c, 0, 0, 0);
}
// async global->LDS, 16B per lane; lds dest must be wave-uniform base (HW adds lane*16)
__device__ __forceinline__ void gll16(const void* g, void* l) {
  __builtin_amdgcn_global_load_lds(
      (const __attribute__((address_space(1))) unsigned int*)g,
      (__attribute__((address_space(3))) unsigned int*)l, 16, 0, 0);
}

// ---------------- K2: tiled transpose f32 -> bf16 of the 3 weight tensors ----------------
__global__ __launch_bounds__(256) void k_transpose(
    const float* __restrict__ wg, const float* __restrict__ wu, const float* __restrict__ wd,
    unsigned short* __restrict__ wgT, unsigned short* __restrict__ wuT,
    unsigned short* __restrict__ wdT)
{
  __shared__ unsigned short lds[64][65];
  int bid = blockIdx.x;
  int m = bid / 4096; int rem = bid % 4096;
  const float* src; unsigned short* dst; int R, C;
  if (m == 0)      { src = wg; dst = wgT; R = 1024; C = 2048; }
  else if (m == 1) { src = wu; dst = wuT; R = 1024; C = 2048; }
  else             { src = wd; dst = wdT; R = 2048; C = 1024; }
  int e = rem / 512; int trem = rem % 512;
  int tcc = C / 64;
  int r0 = (trem / tcc) * 64, c0 = (trem % tcc) * 64;
  size_t ebase = (size_t)e * R * C;
  dst += ebase;
  int tid = threadIdx.x;
  int lr = tid >> 3;            // 0..31
  int lc = (tid & 7) * 8;       // 0..56
#pragma unroll
  for (int p = 0; p < 2; ++p) {
    int row = p * 32 + lr;
    size_t off = ebase + (size_t)(r0 + row) * C + c0 + lc;
    float4 q0 = *(const float4*)&src[off];
    float4 q1 = *(const float4*)&src[off + 4];
    unsigned short tmp[8]; *(u16x8*)tmp = pack8(q0, q1);
#pragma unroll
    for (int j = 0; j < 8; ++j) lds[row][lc + j] = tmp[j];
  }
  __syncthreads();
#pragma unroll
  for (int p = 0; p < 2; ++p) {
    int drow = p * 32 + lr;     // local c index
    unsigned short tmp[8];
#pragma unroll
    for (int j = 0; j < 8; ++j) tmp[j] = lds[lc + j][drow];
    *(u16x8*)&dst[(size_t)(c0 + drow) * R + r0 + lc] = *(const u16x8*)tmp;
  }
}

// ---------------- K3: router + fused x->bf16 cast + fused histogram ----------------
__global__ __launch_bounds__(256) void k_router(
    const float* __restrict__ x, const float* __restrict__ gw,
    unsigned short* __restrict__ xb,
    int* __restrict__ topk_i, float* __restrict__ topk_w,
    int* __restrict__ counts, float* __restrict__ loadw)
{
  int wave = threadIdx.x >> 6, lane = threadIdx.x & 63;
  int t = blockIdx.x * 4 + wave;
  const float* xr = x + (size_t)t * H_DIM;
  float acc[8];
#pragma unroll
  for (int e = 0; e < 8; ++e) acc[e] = 0.f;
#pragma unroll
  for (int it = 0; it < H_DIM / 64; ++it) {
    int h = it * 64 + lane;
    float xv = xr[h];
    xb[(size_t)t * H_DIM + h] = f2bf(xv);       // fused cast (coalesced 128B/wave)
    float4 g0 = *(const float4*)&gw[h * 8];
    float4 g1 = *(const float4*)&gw[h * 8 + 4];
    acc[0] += xv * g0.x; acc[1] += xv * g0.y; acc[2] += xv * g0.z; acc[3] += xv * g0.w;
    acc[4] += xv * g1.x; acc[5] += xv * g1.y; acc[6] += xv * g1.z; acc[7] += xv * g1.w;
  }
#pragma unroll
  for (int off = 32; off > 0; off >>= 1) {
#pragma unroll
    for (int e = 0; e < 8; ++e) acc[e] += __shfl_xor(acc[e], off);
  }
  if (lane == 0) {
    float m = acc[0];
#pragma unroll
    for (int e = 1; e < 8; ++e) m = fmaxf(m, acc[e]);
    float p[8], s = 0.f;
#pragma unroll
    for (int e = 0; e < 8; ++e) { p[e] = __expf(acc[e] - m); s += p[e]; }
    float inv = 1.f / s;
#pragma unroll
    for (int e = 0; e < 8; ++e) p[e] *= inv;
    int i1 = 0;
#pragma unroll
    for (int e = 1; e < 8; ++e) if (p[e] > p[i1]) i1 = e;   // strict > = lowest-index ties
    int i2 = (i1 == 0) ? 1 : 0;
#pragma unroll
    for (int e = 0; e < 8; ++e) if (e != i1 && p[e] > p[i2]) i2 = e;
    topk_i[t * 2]     = i1; topk_i[t * 2 + 1] = i2;
    topk_w[t * 2]     = p[i1]; topk_w[t * 2 + 1] = p[i2];   // RAW probs
    atomicAdd(&counts[i1], 1); atomicAdd(&counts[i2], 1);   // fused histogram
    atomicAdd(&loadw[i1], p[i1]); atomicAdd(&loadw[i2], p[i2]);
  }
}

// ---------------- K4: padded offsets (128) + tile->expert map + aux loss ----------------
__global__ __launch_bounds__(256) void k_offsets(
    const int* __restrict__ counts, const float* __restrict__ loadw,
    int* __restrict__ po, int* __restrict__ tile_e, float* __restrict__ out)
{
  __shared__ int spo[9];
  if (threadIdx.x == 0) {
    int a = 0;
    for (int e = 0; e < 8; ++e) { spo[e] = a; po[e] = a; a += (counts[e] + 127) & ~127; }
    spo[8] = a; po[8] = a;
    float s = 0.f;
    for (int e = 0; e < 8; ++e) s += loadw[e] * (float)counts[e];
    out[(size_t)N_TOK * H_DIM] =
        s * ((float)N_EXP * 1e-3f) / ((float)N_TOK * (float)N_TOK * (float)TOPK);
  }
  __syncthreads();
  int mt = threadIdx.x;
  if (mt < MT_MAX) {
    int te = -1, beg = mt * 128;
    if (beg < spo[8]) {
      for (int e = 0; e < 8; ++e) if (beg >= spo[e] && beg < spo[e + 1]) te = e;
    }
    tile_e[mt] = te;
  }
}

// ---------------- K5: bucket fill ----------------
__global__ __launch_bounds__(256) void k_bucket(
    const int* __restrict__ topk_i, const float* __restrict__ topk_w,
    const int* __restrict__ po, int* __restrict__ cursor,
    int* __restrict__ btok, float* __restrict__ bw, int* __restrict__ tslot)
{
  __shared__ int c[8];
  __shared__ int basee[8];
  int tid = threadIdx.x;
  if (tid < 8) c[tid] = 0;
  __syncthreads();
  int base = blockIdx.x * 1024 + tid * 4;
  int e4[4], r4[4]; float w4[4];
#pragma unroll
  for (int j = 0; j < 4; ++j) {
    int idx = base + j;
    int e = topk_i[idx];
    e4[j] = e;
    r4[j] = atomicAdd(&c[e], 1);
    int t = idx >> 1;
    float p0 = topk_w[t * 2], p1 = topk_w[t * 2 + 1];
    w4[j] = topk_w[idx] / (p0 + p1);
  }
  __syncthreads();
  if (tid < 8) basee[tid] = po[tid] + atomicAdd(&cursor[tid], c[tid]);
  __syncthreads();
#pragma unroll
  for (int j = 0; j < 4; ++j) {
    int idx = base + j;
    int slot = basee[e4[j]] + r4[j];
    btok[slot] = idx >> 1;
    bw[slot] = w4[j];
    tslot[idx] = slot;
  }
}

// ---------------- K6: GEMM1 128x128 dual-B, BK=32, 1 barrier/tile, 2 blocks/CU ----------------
// grid: x = mt (136), y = nt (16); 256 threads = 4 waves (2M x 2N); 48KB LDS (2 buffers)
__global__ __launch_bounds__(256, 2) void k_gemm1(
    const unsigned short* __restrict__ xb,
    const unsigned short* __restrict__ wgT, const unsigned short* __restrict__ wuT,
    const int* __restrict__ btok, const int* __restrict__ tile_e,
    unsigned short* __restrict__ hbuf)
{
  int mt = blockIdx.x, nt = blockIdx.y;
  int e = tile_e[mt];
  if (e < 0) return;
  // buffer (elems): A[128][32] @0, Bg[128][32] @4096, Bu[128][32] @8192; stride 12288; x2
  __shared__ unsigned short lds[24576];
  int tid = threadIdx.x;
  int wave = tid >> 6, lane = tid & 63;
  int wm = wave >> 1, wn = wave & 1;      // 2M x 2N
  int quad = lane >> 4, l16 = lane & 15;

  int rl = lane >> 2;                      // 0..15 row-within-16
  int cw = lane & 3;                       // 16B chunk 0..3
  int scol = (cw ^ ((rl >> 1) & 3)) * 8;   // swizzled global source col (elems)
  const unsigned short* sA[2]; const unsigned short* sBg[2]; const unsigned short* sBu[2];
  unsigned dA[2];
#pragma unroll
  for (int c = 0; c < 2; ++c) {
    int row = wave * 32 + c * 16 + rl;     // 0..127
    int tok = btok[mt * 128 + row];        // pad slots are 0 (memset) -> safe
    sA[c]  = xb + (size_t)tok * H_DIM + scol;
    sBg[c] = wgT + ((size_t)e * I_DIM + nt * 128 + row) * H_DIM + scol;
    sBu[c] = wuT + ((size_t)e * I_DIM + nt * 128 + row) * H_DIM + scol;
    dA[c]  = (unsigned)(wave * 32 + c * 16) * 32;   // wave-uniform elem base
  }
  int fsw = (l16 >> 1) & 3;                // read-side swizzle

  f32x4 accG[4][4], accU[4][4];
  f32x4 z = {0.f, 0.f, 0.f, 0.f};
#pragma unroll
  for (int i = 0; i < 4; ++i)
#pragma unroll
    for (int j = 0; j < 4; ++j) { accG[i][j] = z; accU[i][j] = z; }

  // prologue: stage tile 0 into buffer 0
#pragma unroll
  for (int c = 0; c < 2; ++c) {
    gll16(sA[c],  &lds[dA[c]]);
    gll16(sBg[c], &lds[4096u + dA[c]]);
    gll16(sBu[c], &lds[8192u + dA[c]]);
  }
  WAITV0();
  BAR();

  for (int t = 0; t < 32; ++t) {
    unsigned bo  = (t & 1) ? 12288u : 0u;
    unsigned bo1 = 12288u - bo;
    bf16x8 a[4], g[4], u[4];
#pragma unroll
    for (int m = 0; m < 4; ++m)
      a[m] = *(const bf16x8*)&lds[bo + (unsigned)(wm * 64 + m * 16 + l16) * 32 + ((quad ^ fsw) * 8)];
#pragma unroll
    for (int nf = 0; nf < 4; ++nf) {
      unsigned co = (unsigned)(wn * 64 + nf * 16 + l16) * 32 + ((quad ^ fsw) * 8);
      g[nf] = *(const bf16x8*)&lds[bo + 4096u + co];
      u[nf] = *(const bf16x8*)&lds[bo + 8192u + co];
    }
    if (t < 31) {
      int kel = (t + 1) * 32;
#pragma unroll
      for (int c = 0; c < 2; ++c) {
        gll16(sA[c] + kel,  &lds[bo1 + dA[c]]);
        gll16(sBg[c] + kel, &lds[bo1 + 4096u + dA[c]]);
        gll16(sBu[c] + kel, &lds[bo1 + 8192u + dA[c]]);
      }
    }
    PRIO1();
#pragma unroll
    for (int nf = 0; nf < 4; ++nf)
#pragma unroll
      for (int m = 0; m < 4; ++m) accG[m][nf] = mfma32(a[m], g[nf], accG[m][nf]);
#pragma unroll
    for (int nf = 0; nf < 4; ++nf)
#pragma unroll
      for (int m = 0; m < 4; ++m) accU[m][nf] = mfma32(a[m], u[nf], accU[m][nf]);
    PRIO0();
    WAITV0();      // drain own prefetch (issued this tile); overlapped by other block
    BAR();         // single barrier per K-tile
  }
  // epilogue: SiLU(g)*u -> hbuf
#pragma unroll
  for (int m = 0; m < 4; ++m)
#pragma unroll
    for (int r = 0; r < 4; ++r) {
      int row = mt * 128 + wm * 64 + m * 16 + quad * 4 + r;
      size_t base = (size_t)row * I_DIM + nt * 128 + wn * 64 + l16;
#pragma unroll
      for (int nf = 0; nf < 4; ++nf) {
        float gv = accG[m][nf][r], uv = accU[m][nf][r];
        float sg = gv / (1.f + __expf(-gv));
        hbuf[base + nf * 16] = f2bf(sg * uv);
      }
    }
}

// ---------------- K7: GEMM2 128x128, BK=32, 1 barrier/tile, 3 blocks/CU ----------------
// grid: x = mt (136), y = nt (8); 256 threads = 4 waves (2M x 2N); 32KB LDS (2 buffers)
__global__ __launch_bounds__(256, 3) void k_gemm2(
    const unsigned short* __restrict__ hbuf, const unsigned short* __restrict__ wdT,
    const int* __restrict__ tile_e, unsigned short* __restrict__ obuf)
{
  int mt = blockIdx.x, nt = blockIdx.y;
  int e = tile_e[mt];
  if (e < 0) return;
  // buffer (elems): A[128][32] @0, B[128][32] @4096; stride 8192; x2
  __shared__ unsigned short lds[16384];
  int tid = threadIdx.x;
  int wave = tid >> 6, lane = tid & 63;
  int wm = wave >> 1, wn = wave & 1;      // 2M x 2N
  int quad = lane >> 4, l16 = lane & 15;

  int rl = lane >> 2;
  int cw = lane & 3;
  int scol = (cw ^ ((rl >> 1) & 3)) * 8;
  const unsigned short* sA[2]; const unsigned short* sB[2];
  unsigned dA[2];
#pragma unroll
  for (int c = 0; c < 2; ++c) {
    int row = wave * 32 + c * 16 + rl;
    sA[c] = hbuf + (size_t)(mt * 128 + row) * I_DIM + scol;
    sB[c] = wdT + ((size_t)e * H_DIM + nt * 128 + row) * I_DIM + scol;
    dA[c] = (unsigned)(wave * 32 + c * 16) * 32;
  }
  int fsw = (l16 >> 1) & 3;

  f32x4 acc[4][4];
  f32x4 z = {0.f, 0.f, 0.f, 0.f};
#pragma unroll
  for (int i = 0; i < 4; ++i)
#pragma unroll
    for (int j = 0; j < 4; ++j) acc[i][j] = z;

  // prologue
#pragma unroll
  for (int c = 0; c < 2; ++c) {
    gll16(sA[c], &lds[dA[c]]);
    gll16(sB[c], &lds[4096u + dA[c]]);
  }
  WAITV0();
  BAR();

  for (int t = 0; t < 64; ++t) {
    unsigned bo  = (t & 1) ? 8192u : 0u;
    unsigned bo1 = 8192u - bo;
    bf16x8 a[4], b[4];
#pragma unroll
    for (int m = 0; m < 4; ++m)
      a[m] = *(const bf16x8*)&lds[bo + (unsigned)(wm * 64 + m * 16 + l16) * 32 + ((quad ^ fsw) * 8)];
#pragma unroll
    for (int nf = 0; nf < 4; ++nf)
      b[nf] = *(const bf16x8*)&lds[bo + 4096u + (unsigned)(wn * 64 + nf * 16 + l16) * 32 + ((quad ^ fsw) * 8)];
    if (t < 63) {
      int kel = (t + 1) * 32;
#pragma unroll
      for (int c = 0; c < 2; ++c) {
        gll16(sA[c] + kel, &lds[bo1 + dA[c]]);
        gll16(sB[c] + kel, &lds[bo1 + 4096u + dA[c]]);
      }
    }
    PRIO1();
#pragma unroll
    for (int nf = 0; nf < 4; ++nf)
#pragma unroll
      for (int m = 0; m < 4; ++m) acc[m][nf] = mfma32(a[m], b[nf], acc[m][nf]);
    PRIO0();
    WAITV0();
    BAR();
  }
  // epilogue: bf16 store to obuf
#pragma unroll
  for (int m = 0; m < 4; ++m)
#pragma unroll
    for (int r = 0; r < 4; ++r) {
      int s = mt * 128 + wm * 64 + m * 16 + quad * 4 + r;
      size_t base = (size_t)s * H_DIM + nt * 128 + wn * 64 + l16;
#pragma unroll
      for (int nf = 0; nf < 4; ++nf)
        obuf[base + nf * 16] = f2bf(acc[m][nf][r]);
    }
}

// ---------------- K8: gather-combine y[t] = w0*obuf[s0] + w1*obuf[s1] ----------------
__global__ __launch_bounds__(256) void k_final(
    const unsigned short* __restrict__ obuf, const int* __restrict__ tslot,
    const float* __restrict__ bw, float* __restrict__ y)
{
  int t = blockIdx.x;
  int s0 = tslot[t * 2], s1 = tslot[t * 2 + 1];
  float w0 = bw[s0], w1 = bw[s1];
  int c = threadIdx.x * 4;
  u16x4 o0 = *(const u16x4*)&obuf[(size_t)s0 * H_DIM + c];
  u16x4 o1 = *(const u16x4*)&obuf[(size_t)s1 * H_DIM + c];
  float4 r;
  r.x = w0 * bf2f(o0[0]) + w1 * bf2f(o1[0]);
  r.y = w0 * bf2f(o0[1]) + w1 * bf2f(o1[1]);
  r.z = w0 * bf2f(o0[2]) + w1 * bf2f(o1[2]);
  r.w = w0 * bf2f(o0[3]) + w1 * bf2f(o1[3]);
  *(float4*)&y[(size_t)t * H_DIM + c] = r;
}

extern "C" void kernel_launch(void* const* d_in, const int* in_sizes, int n_in,
                              void* d_out, int out_size, void* d_ws, size_t ws_size,
                              hipStream_t stream)
{
  (void)in_sizes; (void)n_in; (void)out_size; (void)ws_size;
  const float* x  = (const float*)d_in[0];
  const float* gw = (const float*)d_in[1];
  const float* wg = (const float*)d_in[2];
  const float* wu = (const float*)d_in[3];
  const float* wd = (const float*)d_in[4];
  char* ws = (char*)d_ws;

  int*   topk_i = (int*)  (ws + OFF_TOPK_I);
  float* topk_w = (float*)(ws + OFF_TOPK_W);
  int*   counts = (int*)  (ws + OFF_COUNTS);
  float* loadw  = (float*)(ws + OFF_LOAD);
  int*   cursor = (int*)  (ws + OFF_CURSOR);
  int*   po     = (int*)  (ws + OFF_PO);
  int*   tile_e = (int*)  (ws + OFF_TILE_E);
  int*   btok   = (int*)  (ws + OFF_BTOK);
  float* bw     = (float*)(ws + OFF_BW);
  int*   tslot  = (int*)  (ws + OFF_TSLOT);
  unsigned short* wgT  = (unsigned short*)(ws + OFF_WGT);
  unsigned short* wuT  = (unsigned short*)(ws + OFF_WUT);
  unsigned short* wdT  = (unsigned short*)(ws + OFF_WDT);
  unsigned short* hbuf = (unsigned short*)(ws + OFF_HB);
  unsigned short* xb   = (unsigned short*)(ws + OFF_XB);
  unsigned short* obuf = (unsigned short*)(ws + OFF_WGT);  // reuse wgT+wuT (dead after gemm1)
  float* yout = (float*)d_out;

  (void)hipMemsetAsync(ws, 0, CTRL_BYTES, stream);
  k_router<<<N_TOK / 4, 256, 0, stream>>>(x, gw, xb, topk_i, topk_w, counts, loadw);
  k_transpose<<<12288, 256, 0, stream>>>(wg, wu, wd, wgT, wuT, wdT);
  k_offsets<<<1, 256, 0, stream>>>(counts, loadw, po, tile_e, (float*)d_out);
  k_bucket<<<16, 256, 0, stream>>>(topk_i, topk_w, po, cursor, btok, bw, tslot);
  k_gemm1<<<dim3(MT_MAX, I_DIM / 128), 256, 0, stream>>>(xb, wgT, wuT, btok, tile_e, hbuf);
  k_gemm2<<<dim3(MT_MAX, H_DIM / 128), 256, 0, stream>>>(hbuf, wdT, tile_e, obuf);
  k_final<<<N_TOK, 256, 0, stream>>>(obuf, tslot, bw, yout);
}

// Round 5
// 561.203 us; speedup vs baseline: 1.6735x; 1.6735x over previous
//
#include <hip/hip_runtime.h>

// ---------------- problem constants ----------------
#define N_TOK 8192      // B*S tokens
#define H_DIM 1024
#define I_DIM 2048
#define N_EXP 8
#define TOPK  2
#define CAP   18432     // 16384 + 8*256 (per-expert padding to 256)
#define MT_MAX 72       // CAP / 256

// ---------------- workspace layout (bytes) ----------------
#define OFF_TOPK_I 0u          // 16384 i32
#define OFF_TOPK_W 65536u      // 16384 f32 (RAW softmax probs of chosen experts)
#define OFF_COUNTS 131072u     // 8 i32
#define OFF_LOAD   131104u     // 8 f32
#define OFF_CURSOR 131136u     // 8 i32
#define OFF_PO     131168u     // 16 i32
#define OFF_TILE_E 131232u     // 128 i32 (72 used)
#define OFF_BTOK   131744u     // 18432 i32
#define OFF_BW     205472u     // 18432 f32
#define CTRL_BYTES 279200u     // memset covers everything above
#define OFF_TSLOT  279552u     // 16384 i32 — fully overwritten by k_bucket, no memset
#define OFF_WGT  1048576u                      // 8*2048*1024*2 = 33554432
#define OFF_WUT  (OFF_WGT + 33554432u)
#define OFF_WDT  (OFF_WUT + 33554432u)
#define OFF_HB   (OFF_WDT + 33554432u)         // 18432*2048*2 = 75497472
#define OFF_XB   (OFF_HB + 75497472u)          // 8192*1024*2 = 16777216 (x in bf16)
// obuf (18432*1024 bf16 = 37.7 MB) reuses WGT+WUT (dead after gemm1)

typedef __attribute__((ext_vector_type(8))) short bf16x8;
typedef __attribute__((ext_vector_type(8))) unsigned short u16x8;
typedef __attribute__((ext_vector_type(4))) unsigned short u16x4;
typedef __attribute__((ext_vector_type(4))) float f32x4;

#define BAR() __builtin_amdgcn_s_barrier()
#define PRIO1() __builtin_amdgcn_s_setprio(1)
#define PRIO0() __builtin_amdgcn_s_setprio(0)
#define WAITV0() asm volatile("s_waitcnt vmcnt(0)" ::: "memory")
#define WAITV6() asm volatile("s_waitcnt vmcnt(6)" ::: "memory")

__device__ __forceinline__ unsigned short f2bf(float f) {
  union { float f; unsigned int u; } v; v.f = f;
  unsigned int r = (v.u + 0x7FFFu + ((v.u >> 16) & 1u)) >> 16;
  return (unsigned short)r;
}
__device__ __forceinline__ float bf2f(unsigned short u) {
  union { unsigned int u; float f; } v; v.u = ((unsigned int)u) << 16;
  return v.f;
}
__device__ __forceinline__ u16x8 pack8(float4 a, float4 b) {
  u16x8 r;
  r[0] = f2bf(a.x); r[1] = f2bf(a.y); r[2] = f2bf(a.z); r[3] = f2bf(a.w);
  r[4] = f2bf(b.x); r[5] = f2bf(b.y); r[6] = f2bf(b.z); r[7] = f2bf(b.w);
  return r;
}
__device__ __forceinline__ f32x4 mfma32(bf16x8 a, bf16x8 b, f32x4 c) {
  return __builtin_amdgcn_mfma_f32_16x16x32_bf16(a, b, c, 0, 0, 0);
}
// async global->LDS, 16B per lane; lds dest must be wave-uniform base (HW adds lane*16)
__device__ __forceinline__ void gll16(const void* g, void* l) {
  __builtin_amdgcn_global_load_lds(
      (const __attribute__((address_space(1))) unsigned int*)g,
      (__attribute__((address_space(3))) unsigned int*)l, 16, 0, 0);
}

// ---------------- K2: tiled transpose f32 -> bf16 of the 3 weight tensors ----------------
__global__ __launch_bounds__(256) void k_transpose(
    const float* __restrict__ wg, const float* __restrict__ wu, const float* __restrict__ wd,
    unsigned short* __restrict__ wgT, unsigned short* __restrict__ wuT,
    unsigned short* __restrict__ wdT)
{
  __shared__ unsigned short lds[64][65];
  int bid = blockIdx.x;
  int m = bid / 4096; int rem = bid % 4096;
  const float* src; unsigned short* dst; int R, C;
  if (m == 0)      { src = wg; dst = wgT; R = 1024; C = 2048; }
  else if (m == 1) { src = wu; dst = wuT; R = 1024; C = 2048; }
  else             { src = wd; dst = wdT; R = 2048; C = 1024; }
  int e = rem / 512; int trem = rem % 512;
  int tcc = C / 64;
  int r0 = (trem / tcc) * 64, c0 = (trem % tcc) * 64;
  size_t ebase = (size_t)e * R * C;
  dst += ebase;
  int tid = threadIdx.x;
  int lr = tid >> 3;            // 0..31
  int lc = (tid & 7) * 8;       // 0..56
#pragma unroll
  for (int p = 0; p < 2; ++p) {
    int row = p * 32 + lr;
    size_t off = ebase + (size_t)(r0 + row) * C + c0 + lc;
    float4 q0 = *(const float4*)&src[off];
    float4 q1 = *(const float4*)&src[off + 4];
    unsigned short tmp[8]; *(u16x8*)tmp = pack8(q0, q1);
#pragma unroll
    for (int j = 0; j < 8; ++j) lds[row][lc + j] = tmp[j];
  }
  __syncthreads();
#pragma unroll
  for (int p = 0; p < 2; ++p) {
    int drow = p * 32 + lr;     // local c index
    unsigned short tmp[8];
#pragma unroll
    for (int j = 0; j < 8; ++j) tmp[j] = lds[lc + j][drow];
    *(u16x8*)&dst[(size_t)(c0 + drow) * R + r0 + lc] = *(const u16x8*)tmp;
  }
}

// ---------------- K3: router (1 wave/token) + fused x->bf16 cast; NO global atomics ----------------
__global__ __launch_bounds__(256) void k_router(
    const float* __restrict__ x, const float* __restrict__ gw,
    unsigned short* __restrict__ xb,
    int* __restrict__ topk_i, float* __restrict__ topk_w)
{
  int wave = threadIdx.x >> 6, lane = threadIdx.x & 63;
  int t = blockIdx.x * 4 + wave;
  const float* xr = x + (size_t)t * H_DIM;
  float acc[8];
#pragma unroll
  for (int e = 0; e < 8; ++e) acc[e] = 0.f;
#pragma unroll
  for (int it = 0; it < H_DIM / 64; ++it) {
    int h = it * 64 + lane;
    float xv = xr[h];
    xb[(size_t)t * H_DIM + h] = f2bf(xv);       // fused cast (coalesced 128B/wave)
    float4 g0 = *(const float4*)&gw[h * 8];
    float4 g1 = *(const float4*)&gw[h * 8 + 4];
    acc[0] += xv * g0.x; acc[1] += xv * g0.y; acc[2] += xv * g0.z; acc[3] += xv * g0.w;
    acc[4] += xv * g1.x; acc[5] += xv * g1.y; acc[6] += xv * g1.z; acc[7] += xv * g1.w;
  }
#pragma unroll
  for (int off = 32; off > 0; off >>= 1) {
#pragma unroll
    for (int e = 0; e < 8; ++e) acc[e] += __shfl_xor(acc[e], off);
  }
  if (lane == 0) {
    float m = acc[0];
#pragma unroll
    for (int e = 1; e < 8; ++e) m = fmaxf(m, acc[e]);
    float p[8], s = 0.f;
#pragma unroll
    for (int e = 0; e < 8; ++e) { p[e] = __expf(acc[e] - m); s += p[e]; }
    float inv = 1.f / s;
#pragma unroll
    for (int e = 0; e < 8; ++e) p[e] *= inv;
    int i1 = 0;
#pragma unroll
    for (int e = 1; e < 8; ++e) if (p[e] > p[i1]) i1 = e;   // strict > = lowest-index ties
    int i2 = (i1 == 0) ? 1 : 0;
#pragma unroll
    for (int e = 0; e < 8; ++e) if (e != i1 && p[e] > p[i2]) i2 = e;
    topk_i[t * 2]     = i1; topk_i[t * 2 + 1] = i2;
    topk_w[t * 2]     = p[i1]; topk_w[t * 2 + 1] = p[i2];   // RAW probs
  }
}

// ---------------- K3b: histogram via LDS aggregation -> 128 global atomics total ----------------
__global__ __launch_bounds__(256) void k_hist(
    const int* __restrict__ topk_i, const float* __restrict__ topk_w,
    int* __restrict__ counts, float* __restrict__ loadw)
{
  __shared__ int c[8]; __shared__ float l[8];
  int tid = threadIdx.x;
  if (tid < 8) { c[tid] = 0; l[tid] = 0.f; }
  __syncthreads();
  int base = blockIdx.x * 1024 + tid * 4;
#pragma unroll
  for (int j = 0; j < 4; ++j) {
    int e = topk_i[base + j];
    float w = topk_w[base + j];
    atomicAdd(&c[e], 1);
    atomicAdd(&l[e], w);
  }
  __syncthreads();
  if (tid < 8) { atomicAdd(&counts[tid], c[tid]); atomicAdd(&loadw[tid], l[tid]); }
}

// ---------------- K4: padded offsets (256) + tile->expert map + aux loss ----------------
__global__ __launch_bounds__(256) void k_offsets(
    const int* __restrict__ counts, const float* __restrict__ loadw,
    int* __restrict__ po, int* __restrict__ tile_e, float* __restrict__ out)
{
  __shared__ int spo[9];
  if (threadIdx.x == 0) {
    int a = 0;
    for (int e = 0; e < 8; ++e) { spo[e] = a; po[e] = a; a += (counts[e] + 255) & ~255; }
    spo[8] = a; po[8] = a;
    float s = 0.f;
    for (int e = 0; e < 8; ++e) s += loadw[e] * (float)counts[e];
    out[(size_t)N_TOK * H_DIM] =
        s * ((float)N_EXP * 1e-3f) / ((float)N_TOK * (float)N_TOK * (float)TOPK);
  }
  __syncthreads();
  int mt = threadIdx.x;
  if (mt < MT_MAX) {
    int te = -1, beg = mt * 256;
    if (beg < spo[8]) {
      for (int e = 0; e < 8; ++e) if (beg >= spo[e] && beg < spo[e + 1]) te = e;
    }
    tile_e[mt] = te;
  }
}

// ---------------- K5: bucket fill ----------------
__global__ __launch_bounds__(256) void k_bucket(
    const int* __restrict__ topk_i, const float* __restrict__ topk_w,
    const int* __restrict__ po, int* __restrict__ cursor,
    int* __restrict__ btok, float* __restrict__ bw, int* __restrict__ tslot)
{
  __shared__ int c[8];
  __shared__ int basee[8];
  int tid = threadIdx.x;
  if (tid < 8) c[tid] = 0;
  __syncthreads();
  int base = blockIdx.x * 1024 + tid * 4;
  int e4[4], r4[4]; float w4[4];
#pragma unroll
  for (int j = 0; j < 4; ++j) {
    int idx = base + j;
    int e = topk_i[idx];
    e4[j] = e;
    r4[j] = atomicAdd(&c[e], 1);
    int t = idx >> 1;
    float p0 = topk_w[t * 2], p1 = topk_w[t * 2 + 1];
    w4[j] = topk_w[idx] / (p0 + p1);
  }
  __syncthreads();
  if (tid < 8) basee[tid] = po[tid] + atomicAdd(&cursor[tid], c[tid]);
  __syncthreads();
#pragma unroll
  for (int j = 0; j < 4; ++j) {
    int idx = base + j;
    int slot = basee[e4[j]] + r4[j];
    btok[slot] = idx >> 1;
    bw[slot] = w4[j];
    tslot[idx] = slot;
  }
}

// ---------------- K6: GEMM1 256x128, G/U wave-split, 128x64 wave tiles, BK=64 ----------------
// grid: x = nt (16), y = mt (72); 512 threads = 8 waves: waves 0-3 compute G, 4-7 compute U.
// LDS 128KB: 2 buffers x (A[256][64] 32KB + Bg[128][64] 16KB + Bu[128][64] 16KB).
// One stage-issue + one vmcnt(0)+barrier per K-tile; 8-chunk XOR swizzle (src+read, dest linear).
__global__ __launch_bounds__(512, 2) void k_gemm1(
    const unsigned short* __restrict__ xb,
    const unsigned short* __restrict__ wgT, const unsigned short* __restrict__ wuT,
    const int* __restrict__ btok, const int* __restrict__ tile_e,
    unsigned short* __restrict__ hbuf)
{
  int nt = blockIdx.x, mt = blockIdx.y;
  int e = tile_e[mt];
  if (e < 0) return;
  __shared__ unsigned char smem[131072];
  unsigned short* lds = (unsigned short*)smem;   // staging (main loop)
  float* uex = (float*)smem;                     // U-exchange (epilogue, aliases staging)
  int tid = threadIdx.x;
  int wave = tid >> 6, lane = tid & 63;
  int grp = wave >> 2;                 // 0 = G-waves, 1 = U-waves
  int g4 = wave & 3;
  int wm = g4 >> 1, wn = g4 & 1;       // 2M x 2N of 128x64 wave tiles
  int quad = lane >> 4, l16 = lane & 15;
  int lsw = l16 & 7;                   // read-side swizzle key

  // ---- staging geometry (512 threads; chunk = 16B = 8 elems; src chunk XOR row&7) ----
  const unsigned short* srcA[4]; unsigned dstA[4];
#pragma unroll
  for (int c = 0; c < 4; ++c) {
    int idx = c * 512 + wave * 64 + lane;         // 0..2047 over A tile bytes/16
    int row = idx >> 3;                            // 0..255
    int ch  = (idx & 7) ^ (row & 7);               // swizzled source chunk
    int tok = btok[mt * 256 + row];                // pad slots 0 (memset) -> safe
    srcA[c] = xb + (size_t)tok * H_DIM + ch * 8;
    dstA[c] = (unsigned)(c * 512 + wave * 64) * 8; // linear LDS elems (lane adds 16B)
  }
  const unsigned short* srcG[2]; const unsigned short* srcU[2]; unsigned dstB[2];
#pragma unroll
  for (int c = 0; c < 2; ++c) {
    int idx = c * 512 + wave * 64 + lane;          // 0..1023 over B tile
    int col = idx >> 3;                            // 0..127 (B row = output col)
    int ch  = (idx & 7) ^ (col & 7);
    srcG[c] = wgT + ((size_t)e * I_DIM + nt * 128 + col) * H_DIM + ch * 8;
    srcU[c] = wuT + ((size_t)e * I_DIM + nt * 128 + col) * H_DIM + ch * 8;
    dstB[c] = (unsigned)(c * 512 + wave * 64) * 8;
  }
  unsigned boff = grp ? 24576u : 16384u;           // my B region (elems)

  f32x4 acc[8][4];
  f32x4 z = {0.f, 0.f, 0.f, 0.f};
#pragma unroll
  for (int i = 0; i < 8; ++i)
#pragma unroll
    for (int j = 0; j < 4; ++j) acc[i][j] = z;

  // prologue: stage tile 0 -> buffer 0
#pragma unroll
  for (int c = 0; c < 4; ++c) gll16(srcA[c], &lds[dstA[c]]);
#pragma unroll
  for (int c = 0; c < 2; ++c) {
    gll16(srcG[c], &lds[16384u + dstB[c]]);
    gll16(srcU[c], &lds[24576u + dstB[c]]);
  }
  WAITV0();
  BAR();

  for (int t = 0; t < 16; ++t) {
    unsigned bo  = (unsigned)(t & 1) * 32768u;
    unsigned bo1 = bo ^ 32768u;
    if (t < 15) {                                   // stage t+1 early: full-tile latency cover
      int kel = (t + 1) * 64;
#pragma unroll
      for (int c = 0; c < 4; ++c) gll16(srcA[c] + kel, &lds[bo1 + dstA[c]]);
#pragma unroll
      for (int c = 0; c < 2; ++c) {
        gll16(srcG[c] + kel, &lds[bo1 + 16384u + dstB[c]]);
        gll16(srcU[c] + kel, &lds[bo1 + 24576u + dstB[c]]);
      }
    }
    PRIO1();
#pragma unroll
    for (int ks = 0; ks < 2; ++ks) {
      bf16x8 b[4];
#pragma unroll
      for (int nf = 0; nf < 4; ++nf) {
        unsigned col = (unsigned)(wn * 64 + nf * 16 + l16);
        b[nf] = *(const bf16x8*)&lds[bo + boff + col * 64 + (unsigned)(((ks * 4 + quad) ^ lsw) * 8)];
      }
#pragma unroll
      for (int mf = 0; mf < 8; ++mf) {
        unsigned row = (unsigned)(wm * 128 + mf * 16 + l16);
        bf16x8 a = *(const bf16x8*)&lds[bo + row * 64 + (unsigned)(((ks * 4 + quad) ^ lsw) * 8)];
#pragma unroll
        for (int nf = 0; nf < 4; ++nf) acc[mf][nf] = mfma32(a, b[nf], acc[mf][nf]);
      }
    }
    PRIO0();
    WAITV0();        // 8 loads issued a full tile ago -> near-complete
    BAR();
  }

  // epilogue: U-waves dump f32 acc to LDS; G-waves fuse SiLU(g)*u -> hbuf
  if (grp == 1) {
#pragma unroll
    for (int mf = 0; mf < 8; ++mf)
#pragma unroll
      for (int r = 0; r < 4; ++r) {
        int row = wm * 128 + mf * 16 + quad * 4 + r;
#pragma unroll
        for (int nf = 0; nf < 4; ++nf)
          uex[row * 128 + wn * 64 + nf * 16 + l16] = acc[mf][nf][r];
      }
  }
  BAR();
  if (grp == 0) {
#pragma unroll
    for (int mf = 0; mf < 8; ++mf)
#pragma unroll
      for (int r = 0; r < 4; ++r) {
        int row = wm * 128 + mf * 16 + quad * 4 + r;
        size_t base = (size_t)(mt * 256 + row) * I_DIM + nt * 128;
#pragma unroll
        for (int nf = 0; nf < 4; ++nf) {
          float g = acc[mf][nf][r];
          float u = uex[row * 128 + wn * 64 + nf * 16 + l16];
          float sg = g / (1.f + __expf(-g));
          hbuf[base + wn * 64 + nf * 16 + l16] = f2bf(sg * u);
        }
      }
  }
}

// ---------------- K7: GEMM2 256x128, BK=64, 3-buffer counted-vmcnt pipeline (R3-proven) ----------------
// grid: x = nt (8), y = mt (72); 512 threads = 8 waves (2M x 4N); 144KB LDS (3 buffers)
__global__ __launch_bounds__(512, 2) void k_gemm2(
    const unsigned short* __restrict__ hbuf, const unsigned short* __restrict__ wdT,
    const int* __restrict__ tile_e, unsigned short* __restrict__ obuf)
{
  int mt = blockIdx.y, nt = blockIdx.x;
  int e = tile_e[mt];
  if (e < 0) return;
  // buffer: A[256][64] @0, B[128][64] @16384 (elems), 24576 elems/buffer, x3
  __shared__ unsigned short lds[73728];
  int tid = threadIdx.x;
  int wave = tid >> 6, lane = tid & 63;
  int wm = wave >> 2, wn = wave & 3;      // 2M x 4N
  int quad = lane >> 4, l16 = lane & 15;

  int rp = lane >> 3;
  int chunk = (lane & 7) ^ rp;
  const unsigned short* sA[2][2]; const unsigned short* sB[2];
  unsigned dA[2][2], dB[2];
#pragma unroll
  for (int h = 0; h < 2; ++h)
#pragma unroll
    for (int c = 0; c < 2; ++c) {
      int rowp = wave * 16 + c * 8 + rp;
      sA[h][c] = hbuf + (size_t)(mt * 256 + h * 128 + rowp) * I_DIM + chunk * 8;
      dA[h][c] = (unsigned)(h * 128 + wave * 16 + c * 8) * 64;
    }
#pragma unroll
  for (int c = 0; c < 2; ++c) {
    int rowp = wave * 16 + c * 8 + rp;
    sB[c] = wdT + ((size_t)e * H_DIM + nt * 128 + rowp) * I_DIM + chunk * 8;
    dB[c] = (unsigned)(wave * 16 + c * 8) * 64;
  }

  f32x4 acc[8][2];
  f32x4 z = {0.f, 0.f, 0.f, 0.f};
#pragma unroll
  for (int i = 0; i < 8; ++i) { acc[i][0] = z; acc[i][1] = z; }

  int fsw = l16 & 7;
  // prologue: stage tiles 0,1 into buffers 0,1 (6 ops each); wait oldest 6
#pragma unroll
  for (int tt = 0; tt < 2; ++tt) {
    unsigned bo = (unsigned)tt * 24576;
    int kel = tt * 64;
#pragma unroll
    for (int h = 0; h < 2; ++h)
#pragma unroll
      for (int c = 0; c < 2; ++c) gll16(sA[h][c] + kel, &lds[bo + dA[h][c]]);
#pragma unroll
    for (int c = 0; c < 2; ++c) gll16(sB[c] + kel, &lds[bo + 16384 + dB[c]]);
  }
  WAITV6();
  BAR();

  unsigned boA = 0, boB = 24576, boC = 49152;   // read, next, stage-target(t+2)
  for (int t = 0; t < 32; ++t) {
    int kel = (t + 2) * 64;
    bool pf = (t < 30);
    bf16x8 b[2][2];
#pragma unroll
    for (int nf = 0; nf < 2; ++nf)
#pragma unroll
      for (int ks = 0; ks < 2; ++ks) {
        int col = wn * 32 + nf * 16 + l16;
        b[nf][ks] = *(const bf16x8*)&lds[boA + 16384 + col * 64 + (((ks * 4 + quad) ^ fsw) * 8)];
      }
    // ---- P0: A mfr0-3 + MFMA ----
    {
      bf16x8 a[4][2];
#pragma unroll
      for (int m = 0; m < 4; ++m)
#pragma unroll
        for (int ks = 0; ks < 2; ++ks) {
          int row = wm * 128 + m * 16 + l16;
          a[m][ks] = *(const bf16x8*)&lds[boA + row * 64 + (((ks * 4 + quad) ^ fsw) * 8)];
        }
      if (pf) {
#pragma unroll
        for (int h = 0; h < 2; ++h)
#pragma unroll
          for (int c = 0; c < 2; ++c) gll16(sA[h][c] + kel, &lds[boC + dA[h][c]]);
      }
      BAR();
      PRIO1();
#pragma unroll
      for (int m = 0; m < 4; ++m)
#pragma unroll
        for (int nf = 0; nf < 2; ++nf)
#pragma unroll
          for (int ks = 0; ks < 2; ++ks) acc[m][nf] = mfma32(a[m][ks], b[nf][ks], acc[m][nf]);
      PRIO0();
      BAR();
    }
    // ---- P1: A mfr4-7 + MFMA; boundary counted wait ----
    {
      bf16x8 a[4][2];
#pragma unroll
      for (int m = 0; m < 4; ++m)
#pragma unroll
        for (int ks = 0; ks < 2; ++ks) {
          int row = wm * 128 + (4 + m) * 16 + l16;
          a[m][ks] = *(const bf16x8*)&lds[boA + row * 64 + (((ks * 4 + quad) ^ fsw) * 8)];
        }
      if (pf) {
#pragma unroll
        for (int c = 0; c < 2; ++c) gll16(sB[c] + kel, &lds[boC + 16384 + dB[c]]);
      }
      BAR();
      PRIO1();
#pragma unroll
      for (int m = 0; m < 4; ++m)
#pragma unroll
        for (int nf = 0; nf < 2; ++nf)
#pragma unroll
          for (int ks = 0; ks < 2; ++ks) acc[4 + m][nf] = mfma32(a[m][ks], b[nf][ks], acc[4 + m][nf]);
      PRIO0();
    }
    if (pf) { WAITV6(); } else { WAITV0(); }   // never drain to 0 in steady state
    BAR();
    unsigned tmp = boA; boA = boB; boB = boC; boC = tmp;
  }
  // epilogue: bf16 store to obuf
#pragma unroll
  for (int m = 0; m < 8; ++m)
#pragma unroll
    for (int r = 0; r < 4; ++r) {
      int s = mt * 256 + wm * 128 + m * 16 + quad * 4 + r;
      size_t base = (size_t)s * H_DIM + nt * 128 + wn * 32 + l16;
      obuf[base]      = f2bf(acc[m][0][r]);
      obuf[base + 16] = f2bf(acc[m][1][r]);
    }
}

// ---------------- K8: gather-combine y[t] = w0*obuf[s0] + w1*obuf[s1] ----------------
__global__ __launch_bounds__(256) void k_final(
    const unsigned short* __restrict__ obuf, const int* __restrict__ tslot,
    const float* __restrict__ bw, float* __restrict__ y)
{
  int t = blockIdx.x;
  int s0 = tslot[t * 2], s1 = tslot[t * 2 + 1];
  float w0 = bw[s0], w1 = bw[s1];
  int c = threadIdx.x * 4;
  u16x4 o0 = *(const u16x4*)&obuf[(size_t)s0 * H_DIM + c];
  u16x4 o1 = *(const u16x4*)&obuf[(size_t)s1 * H_DIM + c];
  float4 r;
  r.x = w0 * bf2f(o0[0]) + w1 * bf2f(o1[0]);
  r.y = w0 * bf2f(o0[1]) + w1 * bf2f(o1[1]);
  r.z = w0 * bf2f(o0[2]) + w1 * bf2f(o1[2]);
  r.w = w0 * bf2f(o0[3]) + w1 * bf2f(o1[3]);
  *(float4*)&y[(size_t)t * H_DIM + c] = r;
}

extern "C" void kernel_launch(void* const* d_in, const int* in_sizes, int n_in,
                              void* d_out, int out_size, void* d_ws, size_t ws_size,
                              hipStream_t stream)
{
  (void)in_sizes; (void)n_in; (void)out_size; (void)ws_size;
  const float* x  = (const float*)d_in[0];
  const float* gw = (const float*)d_in[1];
  const float* wg = (const float*)d_in[2];
  const float* wu = (const float*)d_in[3];
  const float* wd = (const float*)d_in[4];
  char* ws = (char*)d_ws;

  int*   topk_i = (int*)  (ws + OFF_TOPK_I);
  float* topk_w = (float*)(ws + OFF_TOPK_W);
  int*   counts = (int*)  (ws + OFF_COUNTS);
  float* loadw  = (float*)(ws + OFF_LOAD);
  int*   cursor = (int*)  (ws + OFF_CURSOR);
  int*   po     = (int*)  (ws + OFF_PO);
  int*   tile_e = (int*)  (ws + OFF_TILE_E);
  int*   btok   = (int*)  (ws + OFF_BTOK);
  float* bw     = (float*)(ws + OFF_BW);
  int*   tslot  = (int*)  (ws + OFF_TSLOT);
  unsigned short* wgT  = (unsigned short*)(ws + OFF_WGT);
  unsigned short* wuT  = (unsigned short*)(ws + OFF_WUT);
  unsigned short* wdT  = (unsigned short*)(ws + OFF_WDT);
  unsigned short* hbuf = (unsigned short*)(ws + OFF_HB);
  unsigned short* xb   = (unsigned short*)(ws + OFF_XB);
  unsigned short* obuf = (unsigned short*)(ws + OFF_WGT);  // reuse wgT+wuT (dead after gemm1)
  float* yout = (float*)d_out;

  (void)hipMemsetAsync(ws, 0, CTRL_BYTES, stream);
  k_router<<<N_TOK / 4, 256, 0, stream>>>(x, gw, xb, topk_i, topk_w);
  k_transpose<<<12288, 256, 0, stream>>>(wg, wu, wd, wgT, wuT, wdT);
  k_hist<<<16, 256, 0, stream>>>(topk_i, topk_w, counts, loadw);
  k_offsets<<<1, 256, 0, stream>>>(counts, loadw, po, tile_e, (float*)d_out);
  k_bucket<<<16, 256, 0, stream>>>(topk_i, topk_w, po, cursor, btok, bw, tslot);
  k_gemm1<<<dim3(I_DIM / 128, MT_MAX), 512, 0, stream>>>(xb, wgT, wuT, btok, tile_e, hbuf);
  k_gemm2<<<dim3(H_DIM / 128, MT_MAX), 512, 0, stream>>>(hbuf, wdT, tile_e, obuf);
  k_final<<<N_TOK, 256, 0, stream>>>(obuf, tslot, bw, yout);
}